// Round 4
// baseline (34625.571 us; speedup 1.0000x reference)
//
#include <hip/hip_runtime.h>
#include <hip/hip_cooperative_groups.h>
#include <math.h>

namespace cg = cooperative_groups;

#define BB 256   // batch
#define TT 512   // encoder seq len
#define DD 64    // state dim
#define HH 512   // hidden dim
#define FF 32    // fc_seq_len (decoder steps)

__device__ __forceinline__ float sigmoidf_(float x) { return 1.0f / (1.0f + __expf(-x)); }

struct Smem {
    float hs[16][34];
    float ws[96][34];
};

// Inner-product tile loop; hs/ws are local pointer-to-array views of Smem.
#define GRU_TILE_LOOP(N0, N1)                                              \
    _Pragma("unroll")                                                      \
    for (int k = 0; k < 32; k += 2) {                                      \
        const float2 a0 = *(const float2*)&hs[bb][k];                      \
        const float2 a1 = *(const float2*)&hs[bb + 8][k];                  \
        const float2 w0 = *(const float2*)&ws[jj][k];                      \
        const float2 w1 = *(const float2*)&ws[32 + jj][k];                 \
        const float2 w2 = *(const float2*)&ws[64 + jj][k];                 \
        acc_r0 = fmaf(a0.x, w0.x, acc_r0); acc_r0 = fmaf(a0.y, w0.y, acc_r0); \
        acc_z0 = fmaf(a0.x, w1.x, acc_z0); acc_z0 = fmaf(a0.y, w1.y, acc_z0); \
        N0     = fmaf(a0.x, w2.x, N0);     N0     = fmaf(a0.y, w2.y, N0);     \
        acc_r1 = fmaf(a1.x, w0.x, acc_r1); acc_r1 = fmaf(a1.y, w0.y, acc_r1); \
        acc_z1 = fmaf(a1.x, w1.x, acc_z1); acc_z1 = fmaf(a1.y, w1.y, acc_z1); \
        N1     = fmaf(a1.x, w2.x, N1);     N1     = fmaf(a1.y, w2.y, N1);     \
    }

// GRU cell step body (verified in round 3). Tile [16 batch x 32 hidden] per wg.
// Gates r,z accumulate x-part + h-part combined; n keeps i_n / h_n separate
// because n = tanh(i_n + r * h_n). Biases are hoisted by the caller.
__device__ __forceinline__ void gru_body(
    Smem& sm, int tid, int j0, int b0,
    const float* __restrict__ x, int x_stride,
    const float* __restrict__ h,                    // nullptr == zeros
    const float* __restrict__ W_ih,
    const float* __restrict__ W_hh,
    float br, float bz, float bin, float bhn,
    float* __restrict__ h_out,
    float* __restrict__ h_out2, int h2_stride)
{
    float (*hs)[34] = sm.hs;
    float (*ws)[34] = sm.ws;
    const int jj = tid & 31;
    const int bb = tid >> 5;

    float acc_r0 = 0.f, acc_z0 = 0.f, ghn0 = 0.f, gin0 = 0.f;
    float acc_r1 = 0.f, acc_z1 = 0.f, ghn1 = 0.f, gin1 = 0.f;

    // ---------- x part: K = DD = 64 ----------
    for (int kt = 0; kt < DD; kt += 32) {
        {   // stage x tile [16][32]
            const int r = tid >> 4, c2 = (tid & 15) * 2;
            *(float2*)&hs[r][c2] = *(const float2*)&x[(b0 + r) * x_stride + kt + c2];
        }
        #pragma unroll
        for (int i = 0; i < 6; ++i) {   // stage 96 rows x 32 of W_ih
            const int idx = i * 256 + tid;
            const int r = idx >> 4, c2 = (idx & 15) * 2;
            const int g = r >> 5;
            const int row = g * HH + j0 + (r & 31);
            *(float2*)&ws[r][c2] = *(const float2*)&W_ih[row * DD + kt + c2];
        }
        __syncthreads();
        GRU_TILE_LOOP(gin0, gin1)
        __syncthreads();
    }

    // ---------- h part: K = HH = 512 ----------
    if (h != nullptr) {
        for (int kt = 0; kt < HH; kt += 32) {
            {
                const int r = tid >> 4, c2 = (tid & 15) * 2;
                *(float2*)&hs[r][c2] = *(const float2*)&h[(b0 + r) * HH + kt + c2];
            }
            #pragma unroll
            for (int i = 0; i < 6; ++i) {
                const int idx = i * 256 + tid;
                const int r = idx >> 4, c2 = (idx & 15) * 2;
                const int g = r >> 5;
                const int row = g * HH + j0 + (r & 31);
                *(float2*)&ws[r][c2] = *(const float2*)&W_hh[row * HH + kt + c2];
            }
            __syncthreads();
            GRU_TILE_LOOP(ghn0, ghn1)
            __syncthreads();
        }
    }

    // ---------- epilogue ----------
    const int j = j0 + jj;
    {
        const int b = b0 + bb;
        const float r = sigmoidf_(acc_r0 + br);
        const float z = sigmoidf_(acc_z0 + bz);
        const float hold = h ? h[b * HH + j] : 0.f;
        const float n = tanhf(gin0 + bin + r * (ghn0 + bhn));
        const float hn = (1.f - z) * n + z * hold;
        h_out[b * HH + j] = hn;
        if (h_out2) h_out2[b * h2_stride + j] = hn;
    }
    {
        const int b = b0 + bb + 8;
        const float r = sigmoidf_(acc_r1 + br);
        const float z = sigmoidf_(acc_z1 + bz);
        const float hold = h ? h[b * HH + j] : 0.f;
        const float n = tanhf(gin1 + bin + r * (ghn1 + bhn));
        const float hn = (1.f - z) * n + z * hold;
        h_out[b * HH + j] = hn;
        if (h_out2) h_out2[b * h2_stride + j] = hn;
    }
}

// fc1 + ReLU body: out[b,j] = relu(h.fc1_w^T + b). Tile [16 x 32] per wg.
__device__ __forceinline__ void fc1_body(
    Smem& sm, int tid, int j0, int b0,
    const float* __restrict__ h, const float* __restrict__ w,
    float fb1, float* __restrict__ out)
{
    float (*hs)[34] = sm.hs;
    float (*ws)[34] = sm.ws;
    const int jj = tid & 31, bb = tid >> 5;
    float a0 = 0.f, a1 = 0.f;

    for (int kt = 0; kt < HH; kt += 32) {
        {
            const int r = tid >> 4, c2 = (tid & 15) * 2;
            *(float2*)&hs[r][c2] = *(const float2*)&h[(b0 + r) * HH + kt + c2];
        }
        #pragma unroll
        for (int i = 0; i < 2; ++i) {   // 32 rows x 32
            const int idx = i * 256 + tid;
            const int r = idx >> 4, c2 = (idx & 15) * 2;
            *(float2*)&ws[r][c2] = *(const float2*)&w[(j0 + r) * HH + kt + c2];
        }
        __syncthreads();
        #pragma unroll
        for (int k = 0; k < 32; k += 2) {
            const float2 h0 = *(const float2*)&hs[bb][k];
            const float2 h1 = *(const float2*)&hs[bb + 8][k];
            const float2 w0 = *(const float2*)&ws[jj][k];
            a0 = fmaf(h0.x, w0.x, a0); a0 = fmaf(h0.y, w0.y, a0);
            a1 = fmaf(h1.x, w0.x, a1); a1 = fmaf(h1.y, w0.y, a1);
        }
        __syncthreads();
    }
    out[(b0 + bb) * HH + j0 + jj]     = fmaxf(a0 + fb1, 0.f);
    out[(b0 + bb + 8) * HH + j0 + jj] = fmaxf(a1 + fb1, 0.f);
}

// fc2 body: s[b,d] = a.fc2_w^T + b ; writes sBuf and s_seq slice.
// One wg covers 4 batch rows (only 64 wgs participate in persistent mode).
__device__ __forceinline__ void fc2_body(
    Smem& sm, int tid, int b0,
    const float* __restrict__ a, const float* __restrict__ w,
    float fb2, float* __restrict__ s_buf,
    float* __restrict__ s_out, int s_out_stride)
{
    float (*as)[34] = sm.hs;    // rows 0..3 used
    float (*ws)[34] = sm.ws;    // rows 0..63 used
    const int d = tid & 63, bb = tid >> 6;
    float acc = 0.f;

    for (int kt = 0; kt < HH; kt += 32) {
        if (tid < 64) {
            const int r = tid >> 4, c2 = (tid & 15) * 2;
            *(float2*)&as[r][c2] = *(const float2*)&a[(b0 + r) * HH + kt + c2];
        }
        #pragma unroll
        for (int i = 0; i < 4; ++i) {   // 64 rows x 32
            const int idx = i * 256 + tid;
            const int r = idx >> 4, c2 = (idx & 15) * 2;
            *(float2*)&ws[r][c2] = *(const float2*)&w[r * HH + kt + c2];
        }
        __syncthreads();
        #pragma unroll
        for (int k = 0; k < 32; k += 2) {
            const float2 av = *(const float2*)&as[bb][k];
            const float2 wv = *(const float2*)&ws[d][k];
            acc = fmaf(av.x, wv.x, acc); acc = fmaf(av.y, wv.y, acc);
        }
        __syncthreads();
    }
    const float v = acc + fb2;
    const int b = b0 + bb;
    s_buf[b * DD + d] = v;
    s_out[b * s_out_stride + d] = v;
}

// ---------------- persistent cooperative kernel ----------------
__global__ void __launch_bounds__(256) gru_persistent(
    const float* __restrict__ state_seq,
    const float* __restrict__ W_ih, const float* __restrict__ W_hh,
    const float* __restrict__ b_ih, const float* __restrict__ b_hh,
    const float* __restrict__ fc1_w, const float* __restrict__ fc1_b,
    const float* __restrict__ fc2_w, const float* __restrict__ fc2_b,
    float* __restrict__ out_s, float* __restrict__ out_h,
    float* __restrict__ hA, float* __restrict__ hB,
    float* __restrict__ aBuf, float* __restrict__ sBuf)
{
    cg::grid_group grid = cg::this_grid();
    __shared__ Smem sm;

    const int tid = threadIdx.x;
    const int w = blockIdx.x;          // 0..255
    const int jt = w & 15, bt = w >> 4;
    const int j0 = jt * 32, b0 = bt * 16;

    // hoist constant biases (same for all 543 steps)
    const int j = j0 + (tid & 31);
    const float br  = b_ih[j] + b_hh[j];
    const float bz  = b_ih[HH + j] + b_hh[HH + j];
    const float bin = b_ih[2 * HH + j];
    const float bhn = b_hh[2 * HH + j];
    const float fb1 = fc1_b[j];
    const float fb2 = (w < 64) ? fc2_b[tid & 63] : 0.f;

    // ---- encoder: 512 GRU steps from h0 = 0 ----
    const float* hprev = nullptr;
    for (int t = 0; t < TT; ++t) {
        float* hw = (t & 1) ? hB : hA;
        gru_body(sm, tid, j0, b0, state_seq + t * DD, TT * DD, hprev,
                 W_ih, W_hh, br, bz, bin, bhn,
                 hw, (t == TT - 1) ? out_h : nullptr, FF * HH);
        grid.sync();
        hprev = hw;
    }

    // ---- decoder: 32 fc_predicts, 31 GRU steps ----
    for (int t = 0; t < FF; ++t) {
        fc1_body(sm, tid, j0, b0, hprev, fc1_w, fb1, aBuf);
        grid.sync();
        if (w < 64)
            fc2_body(sm, tid, w * 4, aBuf, fc2_w, fb2, sBuf,
                     out_s + t * DD, FF * DD);
        grid.sync();
        if (t < FF - 1) {
            float* hw = ((TT + t) & 1) ? hB : hA;
            gru_body(sm, tid, j0, b0, sBuf, DD, hprev,
                     W_ih, W_hh, br, bz, bin, bhn,
                     hw, out_h + (t + 1) * HH, FF * HH);
            hprev = hw;
        }
        grid.sync();
    }
}

// ---------------- fallback per-step kernels (round-3-verified path) ----------------
__global__ __launch_bounds__(256) void gru_step(
    const float* __restrict__ x, int x_stride,
    const float* __restrict__ h,
    const float* __restrict__ W_ih, const float* __restrict__ W_hh,
    const float* __restrict__ b_ih, const float* __restrict__ b_hh,
    float* __restrict__ h_out, float* __restrict__ h_out2, int h2_stride)
{
    __shared__ Smem sm;
    const int tid = threadIdx.x;
    const int j0 = blockIdx.x * 32, b0 = blockIdx.y * 16;
    const int j = j0 + (tid & 31);
    const float br  = b_ih[j] + b_hh[j];
    const float bz  = b_ih[HH + j] + b_hh[HH + j];
    const float bin = b_ih[2 * HH + j];
    const float bhn = b_hh[2 * HH + j];
    gru_body(sm, tid, j0, b0, x, x_stride, h, W_ih, W_hh,
             br, bz, bin, bhn, h_out, h_out2, h2_stride);
}

__global__ __launch_bounds__(256) void fc1_relu(
    const float* __restrict__ h, const float* __restrict__ w,
    const float* __restrict__ bias, float* __restrict__ out)
{
    __shared__ Smem sm;
    const int tid = threadIdx.x;
    const int j0 = blockIdx.x * 32, b0 = blockIdx.y * 16;
    fc1_body(sm, tid, j0, b0, h, w, bias[j0 + (tid & 31)], out);
}

__global__ __launch_bounds__(256) void fc2_out(
    const float* __restrict__ a, const float* __restrict__ w,
    const float* __restrict__ bias, float* __restrict__ s_buf,
    float* __restrict__ s_out, int s_out_stride)
{
    __shared__ Smem sm;
    const int tid = threadIdx.x;
    fc2_body(sm, tid, blockIdx.x * 4, a, w, bias[tid & 63], s_buf, s_out, s_out_stride);
}

extern "C" void kernel_launch(void* const* d_in, const int* in_sizes, int n_in,
                              void* d_out, int out_size, void* d_ws, size_t ws_size,
                              hipStream_t stream) {
    const float* state_seq = (const float*)d_in[0];  // [256,512,64]
    const float* W_ih  = (const float*)d_in[1];      // [1536,64]
    const float* W_hh  = (const float*)d_in[2];      // [1536,512]
    const float* b_ih  = (const float*)d_in[3];
    const float* b_hh  = (const float*)d_in[4];
    const float* fc1_w = (const float*)d_in[5];      // [512,512]
    const float* fc1_b = (const float*)d_in[6];
    const float* fc2_w = (const float*)d_in[7];      // [64,512]
    const float* fc2_b = (const float*)d_in[8];

    float* out_s = (float*)d_out;                    // [256, 32, 64]
    float* out_h = out_s + BB * FF * DD;             // [256, 32, 512]

    float* hA   = (float*)d_ws;
    float* hB   = hA + BB * HH;
    float* aBuf = hB + BB * HH;
    float* sBuf = aBuf + BB * HH;

    // ---- preferred: one persistent cooperative kernel ----
    void* args[] = {
        (void*)&state_seq, (void*)&W_ih, (void*)&W_hh, (void*)&b_ih, (void*)&b_hh,
        (void*)&fc1_w, (void*)&fc1_b, (void*)&fc2_w, (void*)&fc2_b,
        (void*)&out_s, (void*)&out_h, (void*)&hA, (void*)&hB, (void*)&aBuf, (void*)&sBuf
    };
    hipError_t err = hipLaunchCooperativeKernel((const void*)gru_persistent,
                                                dim3(256), dim3(256), args, 0, stream);
    if (err == hipSuccess) return;
    (void)hipGetLastError();   // clear sticky error, fall back to multi-launch

    // ---- fallback: verified per-step launch path ----
    const dim3 blk(256);
    const dim3 gruGrid(HH / 32, BB / 16);

    const float* hcur = nullptr;
    for (int t = 0; t < TT; ++t) {
        float* hout = (t & 1) ? hB : hA;
        float* hout2 = (t == TT - 1) ? out_h : nullptr;
        gru_step<<<gruGrid, blk, 0, stream>>>(state_seq + t * DD, TT * DD, hcur,
                                              W_ih, W_hh, b_ih, b_hh,
                                              hout, hout2, FF * HH);
        hcur = hout;
    }
    for (int t = 0; t < FF; ++t) {
        fc1_relu<<<dim3(HH / 32, BB / 16), blk, 0, stream>>>(hcur, fc1_w, fc1_b, aBuf);
        fc2_out<<<dim3(BB / 4), blk, 0, stream>>>(aBuf, fc2_w, fc2_b, sBuf,
                                                  out_s + t * DD, FF * DD);
        if (t < FF - 1) {
            float* hout = (hcur == hA) ? hB : hA;
            gru_step<<<gruGrid, blk, 0, stream>>>(sBuf, DD, hcur,
                                                  W_ih, W_hh, b_ih, b_hh,
                                                  hout, out_h + (t + 1) * HH, FF * HH);
            hcur = hout;
        }
    }
}

// Round 8
// 30945.987 us; speedup vs baseline: 1.1189x; 1.1189x over previous
//
#include <hip/hip_runtime.h>
#include <hip/hip_cooperative_groups.h>
#include <math.h>

namespace cg = cooperative_groups;

#define BB 256   // batch
#define TT 512   // encoder seq len
#define DD 64    // state dim
#define HH 512   // hidden dim
#define FF 32    // fc_seq_len (decoder steps)
#define NWG 256
#define THR 256

__device__ __forceinline__ float sigmoidf_(float x) { return 1.0f / (1.0f + __expf(-x)); }

// ---------------- weight-stationary persistent kernel (grid.sync edition) ----
// wg w: jt = w>>2 (64 j-tiles of 8 cols), g = w&3 (4 batch groups of 64 rows).
// 256 threads: jj = tid>>5 (0..7), bi = tid&31, q in {0,1}: b = b0+bi+32q.
// GRU weights for the wg's 8 j-cols stay in LDS for all 543 steps.
// Sync: cg::grid_group::sync() only (round-4-proven under graph capture).
struct SmemG {
    float w[3][8][578];    // gate weights, cols 0..63 = W_ih, 64..575 = W_hh
    float hbuf[64][34];    // staged x/h tile; stride 34 -> 2-way alias (free)
    float wfc1[8][34];     // fc1 weight tile
};
struct SmemF2 {
    float w[3][8][578];
    float ws2[64][34];     // fc2 weights (64 rows)
    float as2[4][34];      // fc1 activations (4 rows)
};
union SmemU { SmemG g; SmemF2 f2; };   // 65280 B

// stage 64 rows x 32 cols of src (row stride rs) into hbuf-shaped LDS.
__device__ __forceinline__ void stage_issue(float2* pre, const float* __restrict__ src,
                                            int rs, int kc, int b0, int tid) {
    #pragma unroll
    for (int i = 0; i < 4; ++i)
        pre[i] = *(const float2*)&src[(b0 + i * 16 + (tid >> 4)) * rs + kc + (tid & 15) * 2];
}
__device__ __forceinline__ void stage_commit(float (*buf)[34], const float2* pre, int tid) {
    #pragma unroll
    for (int i = 0; i < 4; ++i)
        *(float2*)&buf[i * 16 + (tid >> 4)][(tid & 15) * 2] = pre[i];
}

// one 32-K chunk of the 3 gate GEMMs: 5 ds_read_b64 / 12 FMA per k-pair
__device__ __forceinline__ void gru_chunk(const SmemG& g, int jj, int bi, int kb,
                                          float* ar, float* az, float* an) {
    #pragma unroll
    for (int kk = 0; kk < 32; kk += 2) {
        const float2 w0 = *(const float2*)&g.w[0][jj][kb + kk];
        const float2 w1 = *(const float2*)&g.w[1][jj][kb + kk];
        const float2 w2 = *(const float2*)&g.w[2][jj][kb + kk];
        #pragma unroll
        for (int q = 0; q < 2; ++q) {
            const float2 hv = *(const float2*)&g.hbuf[bi + 32 * q][kk];
            ar[q] = fmaf(hv.x, w0.x, ar[q]); ar[q] = fmaf(hv.y, w0.y, ar[q]);
            az[q] = fmaf(hv.x, w1.x, az[q]); az[q] = fmaf(hv.y, w1.y, az[q]);
            an[q] = fmaf(hv.x, w2.x, an[q]); an[q] = fmaf(hv.y, w2.y, an[q]);
        }
    }
}

// One GRU step for this wg's [64 batch x 8 j] tile. Caller syncs the grid.
__device__ void gru_step_ws(SmemU& sm, int tid, int jj, int bi, int b0, int j,
                            const float* __restrict__ x, int xs,
                            const float* __restrict__ hprev,
                            float br, float bz, float bin, float bhn,
                            float* __restrict__ hnew,
                            float* __restrict__ h2, int h2s) {
    float ar[2] = {0,0}, az[2] = {0,0}, ain[2] = {0,0}, ahn[2] = {0,0};
    float2 pre[4];

    // ---- x part: K 0..63 (weight cols 0..63)
    stage_issue(pre, x, xs, 0, b0, tid);
    stage_commit(sm.g.hbuf, pre, tid);
    __syncthreads();
    stage_issue(pre, x, xs, 32, b0, tid);
    gru_chunk(sm.g, jj, bi, 0, ar, az, ain);
    __syncthreads();
    stage_commit(sm.g.hbuf, pre, tid);
    __syncthreads();
    gru_chunk(sm.g, jj, bi, 32, ar, az, ain);
    __syncthreads();

    // ---- h part: K 0..511 (weight cols 64..575)
    if (hprev) {
        stage_issue(pre, hprev, HH, 0, b0, tid);
        stage_commit(sm.g.hbuf, pre, tid);
        __syncthreads();
        for (int c = 0; c < 16; ++c) {
            if (c < 15) stage_issue(pre, hprev, HH, 32 * (c + 1), b0, tid);
            gru_chunk(sm.g, jj, bi, 64 + 32 * c, ar, az, ahn);
            __syncthreads();
            if (c < 15) { stage_commit(sm.g.hbuf, pre, tid); __syncthreads(); }
        }
    }

    // ---- epilogue: n = tanh(i_n + r*h_n); h' = (1-z)n + z h
    #pragma unroll
    for (int q = 0; q < 2; ++q) {
        const int b = b0 + bi + 32 * q;
        const float r = sigmoidf_(ar[q] + br);
        const float z = sigmoidf_(az[q] + bz);
        const float hold = hprev ? hprev[b * HH + j] : 0.f;
        const float n = tanhf(ain[q] + bin + r * (ahn[q] + bhn));
        const float hn = (1.f - z) * n + z * hold;
        hnew[b * HH + j] = hn;
        if (h2) h2[b * h2s + j] = hn;
    }
}

__device__ void fc1_ws(SmemU& sm, int tid, int jj, int bi, int b0, int j0, int j,
                       const float* __restrict__ hsrc,
                       const float* __restrict__ fc1_w, float fb1,
                       float* __restrict__ aBuf) {
    float acc[2] = {0, 0};
    float2 pre[4], prew;

    stage_issue(pre, hsrc, HH, 0, b0, tid);
    if (tid < 128) prew = *(const float2*)&fc1_w[(j0 + (tid >> 4)) * HH + (tid & 15) * 2];
    stage_commit(sm.g.hbuf, pre, tid);
    if (tid < 128) *(float2*)&sm.g.wfc1[tid >> 4][(tid & 15) * 2] = prew;
    __syncthreads();
    for (int c = 0; c < 16; ++c) {
        if (c < 15) {
            stage_issue(pre, hsrc, HH, 32 * (c + 1), b0, tid);
            if (tid < 128)
                prew = *(const float2*)&fc1_w[(j0 + (tid >> 4)) * HH + 32 * (c + 1) + (tid & 15) * 2];
        }
        #pragma unroll
        for (int kk = 0; kk < 32; kk += 2) {
            const float2 wv = *(const float2*)&sm.g.wfc1[jj][kk];
            #pragma unroll
            for (int q = 0; q < 2; ++q) {
                const float2 hv = *(const float2*)&sm.g.hbuf[bi + 32 * q][kk];
                acc[q] = fmaf(hv.x, wv.x, acc[q]); acc[q] = fmaf(hv.y, wv.y, acc[q]);
            }
        }
        __syncthreads();
        if (c < 15) {
            stage_commit(sm.g.hbuf, pre, tid);
            if (tid < 128) *(float2*)&sm.g.wfc1[tid >> 4][(tid & 15) * 2] = prew;
            __syncthreads();
        }
    }
    #pragma unroll
    for (int q = 0; q < 2; ++q)
        aBuf[(b0 + bi + 32 * q) * HH + j] = fmaxf(acc[q] + fb1, 0.f);
}

// fc2 (wgs with jt<16 only): 4 batch rows b0f..b0f+3, all 64 d.
__device__ void fc2_ws(SmemU& sm, int tid, int b0f, int t,
                       const float* __restrict__ aBuf,
                       const float* __restrict__ fc2_w, float fb2,
                       float* __restrict__ sBuf, float* __restrict__ out_s) {
    const int d = tid & 63, q4 = tid >> 6;
    float acc = 0.f;
    float2 pre[4], prea;

    stage_issue(pre, fc2_w, HH, 0, 0, tid);        // 64 rows of fc2_w
    if (tid < 64) prea = *(const float2*)&aBuf[(b0f + (tid >> 4)) * HH + (tid & 15) * 2];
    stage_commit(sm.f2.ws2, pre, tid);
    if (tid < 64) *(float2*)&sm.f2.as2[tid >> 4][(tid & 15) * 2] = prea;
    __syncthreads();
    for (int c = 0; c < 16; ++c) {
        if (c < 15) {
            stage_issue(pre, fc2_w, HH, 32 * (c + 1), 0, tid);
            if (tid < 64)
                prea = *(const float2*)&aBuf[(b0f + (tid >> 4)) * HH + 32 * (c + 1) + (tid & 15) * 2];
        }
        #pragma unroll
        for (int kk = 0; kk < 32; kk += 2) {
            const float2 wv = *(const float2*)&sm.f2.ws2[d][kk];
            const float2 av = *(const float2*)&sm.f2.as2[q4][kk];
            acc = fmaf(av.x, wv.x, acc); acc = fmaf(av.y, wv.y, acc);
        }
        __syncthreads();
        if (c < 15) {
            stage_commit(sm.f2.ws2, pre, tid);
            if (tid < 64) *(float2*)&sm.f2.as2[tid >> 4][(tid & 15) * 2] = prea;
            __syncthreads();
        }
    }
    const float v = acc + fb2;
    const int b = b0f + q4;
    sBuf[b * DD + d] = v;
    out_s[b * (FF * DD) + t * DD + d] = v;
}

__global__ void __launch_bounds__(THR) gru_ws_persistent(
    const float* __restrict__ state_seq,
    const float* __restrict__ W_ih, const float* __restrict__ W_hh,
    const float* __restrict__ b_ih, const float* __restrict__ b_hh,
    const float* __restrict__ fc1_w, const float* __restrict__ fc1_b,
    const float* __restrict__ fc2_w, const float* __restrict__ fc2_b,
    float* __restrict__ out_s, float* __restrict__ out_h,
    float* __restrict__ hA, float* __restrict__ hB,
    float* __restrict__ aBuf, float* __restrict__ sBuf) {
    cg::grid_group grid = cg::this_grid();
    __shared__ SmemU sm;
    const int tid = threadIdx.x;
    const int w = blockIdx.x;
    const int jt = w >> 2, g = w & 3;
    const int j0 = jt * 8, b0 = g * 64;
    const int jj = tid >> 5, bi = tid & 31;
    const int j = j0 + jj;

    // one-time: this wg's GRU weight slice into LDS (cols 0..63 = W_ih)
    for (int i = tid; i < 3 * 8 * 576; i += THR) {
        const int gg = i / 4608, rem = i - gg * 4608, r = rem / 576, k = rem - r * 576;
        sm.g.w[gg][r][k] = (k < DD) ? W_ih[(gg * HH + j0 + r) * DD + k]
                                    : W_hh[(gg * HH + j0 + r) * HH + (k - DD)];
    }
    const float br  = b_ih[j] + b_hh[j];
    const float bz  = b_ih[HH + j] + b_hh[HH + j];
    const float bin = b_ih[2 * HH + j];
    const float bhn = b_hh[2 * HH + j];
    const float fb1 = fc1_b[j];
    const float fb2 = (jt < 16) ? fc2_b[tid & 63] : 0.f;
    __syncthreads();

    const float* hprev = nullptr;

    // ---- encoder: 512 steps ----
    for (int t = 0; t < TT; ++t) {
        float* hnew = (t & 1) ? hB : hA;
        gru_step_ws(sm, tid, jj, bi, b0, j, state_seq + t * DD, TT * DD, hprev,
                    br, bz, bin, bhn, hnew,
                    (t == TT - 1) ? out_h : nullptr, FF * HH);
        grid.sync();
        hprev = hnew;
    }

    // ---- decoder: 32 fc_predicts, 31 GRU steps ----
    for (int t = 0; t < FF; ++t) {
        fc1_ws(sm, tid, jj, bi, b0, j0, j, hprev, fc1_w, fb1, aBuf);
        grid.sync();
        if (jt < 16)
            fc2_ws(sm, tid, b0 + jt * 4, t, aBuf, fc2_w, fb2, sBuf, out_s);
        grid.sync();
        if (t < FF - 1) {
            float* hnew = ((TT + t) & 1) ? hB : hA;
            gru_step_ws(sm, tid, jj, bi, b0, j, sBuf, DD, hprev,
                        br, bz, bin, bhn, hnew, out_h + (t + 1) * HH, FF * HH);
            grid.sync();
            hprev = hnew;
        }
    }
}

// ---------------- fallback per-step kernels (round-3-verified, 22 ms) ----------------
struct SmemOld { float hs[16][34]; float ws[96][34]; };
#define GRU_TILE_LOOP(N0, N1)                                              \
    _Pragma("unroll")                                                      \
    for (int k = 0; k < 32; k += 2) {                                      \
        const float2 a0 = *(const float2*)&hs[bb][k];                      \
        const float2 a1 = *(const float2*)&hs[bb + 8][k];                  \
        const float2 w0 = *(const float2*)&ws[jj][k];                      \
        const float2 w1 = *(const float2*)&ws[32 + jj][k];                 \
        const float2 w2 = *(const float2*)&ws[64 + jj][k];                 \
        acc_r0 = fmaf(a0.x, w0.x, acc_r0); acc_r0 = fmaf(a0.y, w0.y, acc_r0); \
        acc_z0 = fmaf(a0.x, w1.x, acc_z0); acc_z0 = fmaf(a0.y, w1.y, acc_z0); \
        N0     = fmaf(a0.x, w2.x, N0);     N0     = fmaf(a0.y, w2.y, N0);     \
        acc_r1 = fmaf(a1.x, w0.x, acc_r1); acc_r1 = fmaf(a1.y, w0.y, acc_r1); \
        acc_z1 = fmaf(a1.x, w1.x, acc_z1); acc_z1 = fmaf(a1.y, w1.y, acc_z1); \
        N1     = fmaf(a1.x, w2.x, N1);     N1     = fmaf(a1.y, w2.y, N1);     \
    }

__global__ __launch_bounds__(256) void gru_step(
    const float* __restrict__ x, int x_stride, const float* __restrict__ h,
    const float* __restrict__ W_ih, const float* __restrict__ W_hh,
    const float* __restrict__ b_ih, const float* __restrict__ b_hh,
    float* __restrict__ h_out, float* __restrict__ h_out2, int h2s) {
    __shared__ SmemOld sm;
    float (*hs)[34] = sm.hs; float (*ws)[34] = sm.ws;
    const int tid = threadIdx.x;
    const int jj = tid & 31, bb = tid >> 5;
    const int j0 = blockIdx.x * 32, b0 = blockIdx.y * 16;
    float acc_r0 = 0.f, acc_z0 = 0.f, ghn0 = 0.f, gin0 = 0.f;
    float acc_r1 = 0.f, acc_z1 = 0.f, ghn1 = 0.f, gin1 = 0.f;
    for (int kt = 0; kt < DD; kt += 32) {
        { const int r = tid >> 4, c2 = (tid & 15) * 2;
          *(float2*)&hs[r][c2] = *(const float2*)&x[(b0 + r) * x_stride + kt + c2]; }
        #pragma unroll
        for (int i = 0; i < 6; ++i) {
            const int idx = i * 256 + tid, r = idx >> 4, c2 = (idx & 15) * 2;
            const int row = (r >> 5) * HH + j0 + (r & 31);
            *(float2*)&ws[r][c2] = *(const float2*)&W_ih[row * DD + kt + c2];
        }
        __syncthreads(); GRU_TILE_LOOP(gin0, gin1) __syncthreads();
    }
    if (h != nullptr) {
        for (int kt = 0; kt < HH; kt += 32) {
            { const int r = tid >> 4, c2 = (tid & 15) * 2;
              *(float2*)&hs[r][c2] = *(const float2*)&h[(b0 + r) * HH + kt + c2]; }
            #pragma unroll
            for (int i = 0; i < 6; ++i) {
                const int idx = i * 256 + tid, r = idx >> 4, c2 = (idx & 15) * 2;
                const int row = (r >> 5) * HH + j0 + (r & 31);
                *(float2*)&ws[r][c2] = *(const float2*)&W_hh[row * HH + kt + c2];
            }
            __syncthreads(); GRU_TILE_LOOP(ghn0, ghn1) __syncthreads();
        }
    }
    const int j = j0 + jj;
    const float br = b_ih[j] + b_hh[j], bz = b_ih[HH + j] + b_hh[HH + j];
    const float bin = b_ih[2 * HH + j], bhn = b_hh[2 * HH + j];
    { const int b = b0 + bb;
      const float r = sigmoidf_(acc_r0 + br), z = sigmoidf_(acc_z0 + bz);
      const float hold = h ? h[b * HH + j] : 0.f;
      const float n = tanhf(gin0 + bin + r * (ghn0 + bhn));
      const float hn = (1.f - z) * n + z * hold;
      h_out[b * HH + j] = hn; if (h_out2) h_out2[b * h2s + j] = hn; }
    { const int b = b0 + bb + 8;
      const float r = sigmoidf_(acc_r1 + br), z = sigmoidf_(acc_z1 + bz);
      const float hold = h ? h[b * HH + j] : 0.f;
      const float n = tanhf(gin1 + bin + r * (ghn1 + bhn));
      const float hn = (1.f - z) * n + z * hold;
      h_out[b * HH + j] = hn; if (h_out2) h_out2[b * h2s + j] = hn; }
}

__global__ __launch_bounds__(256) void fc1_relu(
    const float* __restrict__ h, const float* __restrict__ wsrc,
    const float* __restrict__ bias, float* __restrict__ out) {
    __shared__ SmemOld sm;
    float (*hs)[34] = sm.hs; float (*ws)[34] = sm.ws;
    const int tid = threadIdx.x;
    const int jj = tid & 31, bb = tid >> 5;
    const int j0 = blockIdx.x * 32, b0 = blockIdx.y * 16;
    float a0 = 0.f, a1 = 0.f;
    for (int kt = 0; kt < HH; kt += 32) {
        { const int r = tid >> 4, c2 = (tid & 15) * 2;
          *(float2*)&hs[r][c2] = *(const float2*)&h[(b0 + r) * HH + kt + c2]; }
        #pragma unroll
        for (int i = 0; i < 2; ++i) {
            const int idx = i * 256 + tid, r = idx >> 4, c2 = (idx & 15) * 2;
            *(float2*)&ws[r][c2] = *(const float2*)&wsrc[(j0 + r) * HH + kt + c2];
        }
        __syncthreads();
        #pragma unroll
        for (int k = 0; k < 32; k += 2) {
            const float2 h0 = *(const float2*)&hs[bb][k];
            const float2 h1 = *(const float2*)&hs[bb + 8][k];
            const float2 w0 = *(const float2*)&ws[jj][k];
            a0 = fmaf(h0.x, w0.x, a0); a0 = fmaf(h0.y, w0.y, a0);
            a1 = fmaf(h1.x, w0.x, a1); a1 = fmaf(h1.y, w0.y, a1);
        }
        __syncthreads();
    }
    const float b = bias[j0 + jj];
    out[(b0 + bb) * HH + j0 + jj]     = fmaxf(a0 + b, 0.f);
    out[(b0 + bb + 8) * HH + j0 + jj] = fmaxf(a1 + b, 0.f);
}

__global__ __launch_bounds__(256) void fc2_out(
    const float* __restrict__ a, const float* __restrict__ wsrc,
    const float* __restrict__ bias, float* __restrict__ s_buf,
    float* __restrict__ s_out, int s_stride) {
    __shared__ SmemOld sm;
    float (*as)[34] = sm.hs; float (*ws)[34] = sm.ws;
    const int tid = threadIdx.x;
    const int d = tid & 63, bb = tid >> 6;
    const int b0 = blockIdx.x * 4;
    float acc = 0.f;
    for (int kt = 0; kt < HH; kt += 32) {
        if (tid < 64) { const int r = tid >> 4, c2 = (tid & 15) * 2;
            *(float2*)&as[r][c2] = *(const float2*)&a[(b0 + r) * HH + kt + c2]; }
        #pragma unroll
        for (int i = 0; i < 4; ++i) {
            const int idx = i * 256 + tid, r = idx >> 4, c2 = (idx & 15) * 2;
            *(float2*)&ws[r][c2] = *(const float2*)&wsrc[r * HH + kt + c2];
        }
        __syncthreads();
        #pragma unroll
        for (int k = 0; k < 32; k += 2) {
            const float2 av = *(const float2*)&as[bb][k];
            const float2 wv = *(const float2*)&ws[d][k];
            acc = fmaf(av.x, wv.x, acc); acc = fmaf(av.y, wv.y, acc);
        }
        __syncthreads();
    }
    const float v = acc + bias[d];
    s_buf[(b0 + bb) * DD + d] = v;
    s_out[(b0 + bb) * s_stride + d] = v;
}

extern "C" void kernel_launch(void* const* d_in, const int* in_sizes, int n_in,
                              void* d_out, int out_size, void* d_ws, size_t ws_size,
                              hipStream_t stream) {
    const float* state_seq = (const float*)d_in[0];
    const float* W_ih  = (const float*)d_in[1];
    const float* W_hh  = (const float*)d_in[2];
    const float* b_ih  = (const float*)d_in[3];
    const float* b_hh  = (const float*)d_in[4];
    const float* fc1_w = (const float*)d_in[5];
    const float* fc1_b = (const float*)d_in[6];
    const float* fc2_w = (const float*)d_in[7];
    const float* fc2_b = (const float*)d_in[8];

    float* out_s = (float*)d_out;                 // [256, 32, 64]
    float* out_h = out_s + BB * FF * DD;          // [256, 32, 512]

    float* hA   = (float*)d_ws;
    float* hB   = hA + BB * HH;
    float* aBuf = hB + BB * HH;
    float* sBuf = aBuf + BB * HH;
    const size_t need = (size_t)(3 * BB * HH + BB * DD) * 4;

    bool coop_ok = false;
    if (ws_size >= need) {
        // SINGLE graph node: coop kernel with grid.sync only (round-4-proven).
        void* args[] = {
            (void*)&state_seq, (void*)&W_ih, (void*)&W_hh, (void*)&b_ih, (void*)&b_hh,
            (void*)&fc1_w, (void*)&fc1_b, (void*)&fc2_w, (void*)&fc2_b,
            (void*)&out_s, (void*)&out_h, (void*)&hA, (void*)&hB,
            (void*)&aBuf, (void*)&sBuf };
        hipError_t e = hipLaunchCooperativeKernel((const void*)gru_ws_persistent,
                                                  dim3(NWG), dim3(THR), args, 0, stream);
        coop_ok = (e == hipSuccess);
        if (!coop_ok) (void)hipGetLastError();
    }
    if (coop_ok) return;

    // fallback: verified per-step path
    const dim3 blk(256);
    const dim3 gruGrid(HH / 32, BB / 16);
    const float* hcur = nullptr;
    for (int t = 0; t < TT; ++t) {
        float* hout = (t & 1) ? hB : hA;
        float* hout2 = (t == TT - 1) ? out_h : nullptr;
        gru_step<<<gruGrid, blk, 0, stream>>>(state_seq + t * DD, TT * DD, hcur,
                                              W_ih, W_hh, b_ih, b_hh, hout, hout2, FF * HH);
        hcur = hout;
    }
    for (int t = 0; t < FF; ++t) {
        fc1_relu<<<dim3(HH / 32, BB / 16), blk, 0, stream>>>(hcur, fc1_w, fc1_b, aBuf);
        fc2_out<<<dim3(BB / 4), blk, 0, stream>>>(aBuf, fc2_w, fc2_b, sBuf,
                                                  out_s + t * DD, FF * DD);
        if (t < FF - 1) {
            float* hout = (hcur == hA) ? hB : hA;
            gru_step<<<gruGrid, blk, 0, stream>>>(sBuf, DD, hcur, W_ih, W_hh, b_ih, b_hh,
                                                  hout, out_h + (t + 1) * HH, FF * HH);
            hcur = hout;
        }
    }
}

// Round 9
// 17358.902 us; speedup vs baseline: 1.9947x; 1.7827x over previous
//
#include <hip/hip_runtime.h>
#include <math.h>

#define BB 256   // batch
#define TT 512   // encoder seq len
#define DD 64    // state dim
#define HH 512   // hidden dim
#define FF 32    // fc_seq_len (decoder steps)

__device__ __forceinline__ float sigmoidf_(float x) { return 1.0f / (1.0f + __expf(-x)); }

// ---------------- per-step GRU kernel, weight-slice stationary in LDS ----------------
// grid (64, 4): jt = blockIdx.x (8 j-cols), g = blockIdx.y (64 batch rows).
// 256 thr: jj = tid>>5 (0..7), bi = tid&31, q in {0,1}: rows b0+bi, b0+bi+32.
// Per thread: 3 gates x 2 rows = 6 accumulators; 5 ds_read_b64 per 12 FMA.
// Kernel-launch boundaries are the cross-wg h(t) sync (graph-replay gap ~µs,
// vs ~45 µs measured for cg::grid.sync in round 8).
struct SmemW {
    float w[3][8][580];    // stride 580: rows 16B-multiples (b128 writes), banks 4jj+k conflict-free
    float hbuf[64][34];    // stride 34: rows r,r+16 alias -> 2-way b64 (free-ish, m136)
};                         // 55680 + 8704 = 64384 B <= 64 KiB

// stage 64 rows x 32 cols of src (row stride rs) into hbuf.
__device__ __forceinline__ void stage_issue(float2* pre, const float* __restrict__ src,
                                            int rs, int kc, int b0, int tid) {
    #pragma unroll
    for (int i = 0; i < 4; ++i)
        pre[i] = *(const float2*)&src[(b0 + i * 16 + (tid >> 4)) * rs + kc + (tid & 15) * 2];
}
__device__ __forceinline__ void stage_commit(float (*buf)[34], const float2* pre, int tid) {
    #pragma unroll
    for (int i = 0; i < 4; ++i)
        *(float2*)&buf[i * 16 + (tid >> 4)][(tid & 15) * 2] = pre[i];
}

// one 32-K chunk of the 3 gate GEMMs
__device__ __forceinline__ void gru_chunk(const SmemW& g, int jj, int bi, int kb,
                                          float* ar, float* az, float* an) {
    #pragma unroll
    for (int kk = 0; kk < 32; kk += 2) {
        const float2 w0 = *(const float2*)&g.w[0][jj][kb + kk];
        const float2 w1 = *(const float2*)&g.w[1][jj][kb + kk];
        const float2 w2 = *(const float2*)&g.w[2][jj][kb + kk];
        #pragma unroll
        for (int q = 0; q < 2; ++q) {
            const float2 hv = *(const float2*)&g.hbuf[bi + 32 * q][kk];
            ar[q] = fmaf(hv.x, w0.x, ar[q]); ar[q] = fmaf(hv.y, w0.y, ar[q]);
            az[q] = fmaf(hv.x, w1.x, az[q]); az[q] = fmaf(hv.y, w1.y, az[q]);
            an[q] = fmaf(hv.x, w2.x, an[q]); an[q] = fmaf(hv.y, w2.y, an[q]);
        }
    }
}

__global__ __launch_bounds__(256) void gru_step_w(
    const float* __restrict__ x, int xs,             // [BB, *] rows at stride xs
    const float* __restrict__ h,                     // [BB, HH] or nullptr (zeros)
    const float* __restrict__ W_ih, const float* __restrict__ W_hh,
    const float* __restrict__ b_ih, const float* __restrict__ b_hh,
    float* __restrict__ hnew,                        // [BB, HH]
    float* __restrict__ h2, int h2s)                 // optional extra write (h_seq)
{
    __shared__ SmemW sm;
    const int tid = threadIdx.x;
    const int j0 = blockIdx.x * 8, b0 = blockIdx.y * 64;
    const int jj = tid >> 5, bi = tid & 31;
    const int j = j0 + jj;

    // ---- W slice -> LDS: 3 gates x 8 rows x 576 K = 3456 float4s.
    // i4: gg = i4/1152, r = (i4%1152)/144, k4 = i4%144; k4<16 -> W_ih else W_hh.
    {
        #pragma unroll
        for (int half = 0; half < 2; ++half) {
            float4 tmp[7];
            #pragma unroll
            for (int u = 0; u < 7; ++u) {
                const int i4 = (half * 7 + u) * 256 + tid;
                if (i4 < 3456) {
                    const int gg = i4 / 1152, rem = i4 - gg * 1152;
                    const int r = rem / 144, k4 = rem - r * 144;
                    const float* src = (k4 < 16)
                        ? &W_ih[(gg * HH + j0 + r) * DD + k4 * 4]
                        : &W_hh[(gg * HH + j0 + r) * HH + (k4 - 16) * 4];
                    tmp[u] = *(const float4*)src;
                }
            }
            #pragma unroll
            for (int u = 0; u < 7; ++u) {
                const int i4 = (half * 7 + u) * 256 + tid;
                if (i4 < 3456) {
                    const int gg = i4 / 1152, rem = i4 - gg * 1152;
                    const int r = rem / 144, k4 = rem - r * 144;
                    *(float4*)&sm.w[gg][r][k4 * 4] = tmp[u];
                }
            }
        }
    }
    const float br  = b_ih[j] + b_hh[j];
    const float bz  = b_ih[HH + j] + b_hh[HH + j];
    const float bin = b_ih[2 * HH + j];
    const float bhn = b_hh[2 * HH + j];

    float ar[2] = {0,0}, az[2] = {0,0}, ain[2] = {0,0}, ahn[2] = {0,0};
    float2 pre[4];

    // ---- x part: K 0..63 (weight cols 0..63)
    stage_issue(pre, x, xs, 0, b0, tid);
    stage_commit(sm.hbuf, pre, tid);
    __syncthreads();                                  // covers W load + hbuf c0
    stage_issue(pre, x, xs, 32, b0, tid);
    gru_chunk(sm, jj, bi, 0, ar, az, ain);
    __syncthreads();
    stage_commit(sm.hbuf, pre, tid);
    __syncthreads();
    gru_chunk(sm, jj, bi, 32, ar, az, ain);
    __syncthreads();

    // ---- h part: K 0..511 (weight cols 64..575)
    if (h) {
        stage_issue(pre, h, HH, 0, b0, tid);
        stage_commit(sm.hbuf, pre, tid);
        __syncthreads();
        for (int c = 0; c < 16; ++c) {
            if (c < 15) stage_issue(pre, h, HH, 32 * (c + 1), b0, tid);
            gru_chunk(sm, jj, bi, 64 + 32 * c, ar, az, ahn);
            __syncthreads();
            if (c < 15) { stage_commit(sm.hbuf, pre, tid); __syncthreads(); }
        }
    }

    // ---- epilogue: n = tanh(i_n + r*h_n); h' = (1-z)n + z h
    #pragma unroll
    for (int q = 0; q < 2; ++q) {
        const int b = b0 + bi + 32 * q;
        const float r = sigmoidf_(ar[q] + br);
        const float z = sigmoidf_(az[q] + bz);
        const float hold = h ? h[b * HH + j] : 0.f;
        const float n = tanhf(ain[q] + bin + r * (ahn[q] + bhn));
        const float hn = (1.f - z) * n + z * hold;
        hnew[b * HH + j] = hn;
        if (h2) h2[b * h2s + j] = hn;
    }
}

// ---------------- fc kernels (round-3-verified) ----------------
struct SmemOld { float hs[16][34]; float ws[96][34]; };

__global__ __launch_bounds__(256) void fc1_relu(
    const float* __restrict__ h, const float* __restrict__ wsrc,
    const float* __restrict__ bias, float* __restrict__ out) {
    __shared__ SmemOld sm;
    float (*hs)[34] = sm.hs; float (*ws)[34] = sm.ws;
    const int tid = threadIdx.x;
    const int jj = tid & 31, bb = tid >> 5;
    const int j0 = blockIdx.x * 32, b0 = blockIdx.y * 16;
    float a0 = 0.f, a1 = 0.f;
    for (int kt = 0; kt < HH; kt += 32) {
        { const int r = tid >> 4, c2 = (tid & 15) * 2;
          *(float2*)&hs[r][c2] = *(const float2*)&h[(b0 + r) * HH + kt + c2]; }
        #pragma unroll
        for (int i = 0; i < 2; ++i) {
            const int idx = i * 256 + tid, r = idx >> 4, c2 = (idx & 15) * 2;
            *(float2*)&ws[r][c2] = *(const float2*)&wsrc[(j0 + r) * HH + kt + c2];
        }
        __syncthreads();
        #pragma unroll
        for (int k = 0; k < 32; k += 2) {
            const float2 h0 = *(const float2*)&hs[bb][k];
            const float2 h1 = *(const float2*)&hs[bb + 8][k];
            const float2 w0 = *(const float2*)&ws[jj][k];
            a0 = fmaf(h0.x, w0.x, a0); a0 = fmaf(h0.y, w0.y, a0);
            a1 = fmaf(h1.x, w0.x, a1); a1 = fmaf(h1.y, w0.y, a1);
        }
        __syncthreads();
    }
    const float b = bias[j0 + jj];
    out[(b0 + bb) * HH + j0 + jj]     = fmaxf(a0 + b, 0.f);
    out[(b0 + bb + 8) * HH + j0 + jj] = fmaxf(a1 + b, 0.f);
}

__global__ __launch_bounds__(256) void fc2_out(
    const float* __restrict__ a, const float* __restrict__ wsrc,
    const float* __restrict__ bias, float* __restrict__ s_buf,
    float* __restrict__ s_out, int s_stride) {
    __shared__ SmemOld sm;
    float (*as)[34] = sm.hs; float (*ws)[34] = sm.ws;
    const int tid = threadIdx.x;
    const int d = tid & 63, bb = tid >> 6;
    const int b0 = blockIdx.x * 4;
    float acc = 0.f;
    for (int kt = 0; kt < HH; kt += 32) {
        if (tid < 64) { const int r = tid >> 4, c2 = (tid & 15) * 2;
            *(float2*)&as[r][c2] = *(const float2*)&a[(b0 + r) * HH + kt + c2]; }
        #pragma unroll
        for (int i = 0; i < 4; ++i) {
            const int idx = i * 256 + tid, r = idx >> 4, c2 = (idx & 15) * 2;
            *(float2*)&ws[r][c2] = *(const float2*)&wsrc[r * HH + kt + c2];
        }
        __syncthreads();
        #pragma unroll
        for (int k = 0; k < 32; k += 2) {
            const float2 av = *(const float2*)&as[bb][k];
            const float2 wv = *(const float2*)&ws[d][k];
            acc = fmaf(av.x, wv.x, acc); acc = fmaf(av.y, wv.y, acc);
        }
        __syncthreads();
    }
    const float v = acc + bias[d];
    s_buf[(b0 + bb) * DD + d] = v;
    s_out[(b0 + bb) * s_stride + d] = v;
}

extern "C" void kernel_launch(void* const* d_in, const int* in_sizes, int n_in,
                              void* d_out, int out_size, void* d_ws, size_t ws_size,
                              hipStream_t stream) {
    const float* state_seq = (const float*)d_in[0];  // [256,512,64]
    const float* W_ih  = (const float*)d_in[1];      // [1536,64]
    const float* W_hh  = (const float*)d_in[2];      // [1536,512]
    const float* b_ih  = (const float*)d_in[3];
    const float* b_hh  = (const float*)d_in[4];
    const float* fc1_w = (const float*)d_in[5];      // [512,512]
    const float* fc1_b = (const float*)d_in[6];
    const float* fc2_w = (const float*)d_in[7];      // [64,512]
    const float* fc2_b = (const float*)d_in[8];

    float* out_s = (float*)d_out;                    // [256, 32, 64]
    float* out_h = out_s + BB * FF * DD;             // [256, 32, 512]

    float* hA   = (float*)d_ws;
    float* hB   = hA + BB * HH;
    float* aBuf = hB + BB * HH;
    float* sBuf = aBuf + BB * HH;

    const dim3 blk(256);
    const dim3 gruGrid(HH / 8, BB / 64);             // (64, 4)

    // ---- encoder: 512 per-step launches (launch boundary = h sync) ----
    const float* hcur = nullptr;
    for (int t = 0; t < TT; ++t) {
        float* hout = (t & 1) ? hB : hA;
        float* hout2 = (t == TT - 1) ? out_h : nullptr;   // h_seq[:,0,:]
        gru_step_w<<<gruGrid, blk, 0, stream>>>(state_seq + t * DD, TT * DD, hcur,
                                                W_ih, W_hh, b_ih, b_hh,
                                                hout, hout2, FF * HH);
        hcur = hout;
    }

    // ---- decoder: 32 fc_predicts, 31 GRU steps ----
    for (int t = 0; t < FF; ++t) {
        fc1_relu<<<dim3(HH / 32, BB / 16), blk, 0, stream>>>(hcur, fc1_w, fc1_b, aBuf);
        fc2_out<<<dim3(BB / 4), blk, 0, stream>>>(aBuf, fc2_w, fc2_b, sBuf,
                                                  out_s + t * DD, FF * DD);
        if (t < FF - 1) {
            float* hout = (hcur == hA) ? hB : hA;
            gru_step_w<<<gruGrid, blk, 0, stream>>>(sBuf, DD, hcur,
                                                    W_ih, W_hh, b_ih, b_hh,
                                                    hout, out_h + (t + 1) * HH, FF * HH);
            hcur = hout;
        }
    }
}